// Round 1
// baseline (73.521 us; speedup 1.0000x reference)
//
#include <hip/hip_runtime.h>
#include <math.h>

#define N_GAUSS 2048
#define IMG_H 512
#define IMG_W 512

// Tile geometry: one pixel per thread, 64x8 tile per 512-thread block.
// 64-wide rows => each wave's stores are 64 contiguous floats per plane.
#define TILE_W 64
#define TILE_H 8
#define NTHREADS (TILE_W * TILE_H)   // 512
#define CHUNK_G 512                  // gaussians culled per pass (1 per thread)
#define N_CHUNKS (N_GAUSS / CHUNK_G) // 4

__global__ __launch_bounds__(NTHREADS) void fused_splat_kernel(
    const float* __restrict__ xyz,
    const float* __restrict__ chol,
    const float* __restrict__ opacity,
    const float* __restrict__ fdc,
    float* __restrict__ out)
{
    // SoA survivor list in LDS; eval reads are wave-uniform => broadcast, no conflicts
    __shared__ float s_cx[CHUNK_G], s_cy[CHUNK_G];
    __shared__ float s_h0[CHUNK_G], s_c1[CHUNK_G], s_h2[CHUNK_G];
    __shared__ float s_op[CHUNK_G];
    __shared__ float s_cr[CHUNK_G], s_cg[CHUNK_G], s_cb[CHUNK_G];
    __shared__ int   s_cnt;

    const int tid = threadIdx.x;
    const int x = blockIdx.x * TILE_W + (tid & (TILE_W - 1));
    const int y = blockIdx.y * TILE_H + (tid >> 6);
    const float wf = (float)x + 0.5f;
    const float hf = (float)y + 0.5f;

    const int tx0 = blockIdx.x * TILE_W;
    const int tx1 = tx0 + TILE_W - 1;
    const int ty0 = blockIdx.y * TILE_H;
    const int ty1 = ty0 + TILE_H - 1;

    float accr = 0.f, accg = 0.f, accb = 0.f;

    for (int c = 0; c < N_CHUNKS; ++c) {
        __syncthreads();               // prev-chunk eval done before LDS reuse
        if (tid == 0) s_cnt = 0;
        __syncthreads();

        // ---- cull phase: one gaussian per thread ----
        const int g = c * CHUNK_G + tid;
        float mx = tanhf(xyz[2 * g]);
        float my = tanhf(xyz[2 * g + 1]);
        float l1 = chol[3 * g]     + 0.5f;   // cholesky_bound = [0.5, 0, 0.5]
        float l2 = chol[3 * g + 1];
        float l3 = chol[3 * g + 2] + 0.5f;

        float s11 = l1 * l1;
        float s12 = l1 * l2;
        float s22 = l2 * l2 + l3 * l3;
        float det = s11 * s22 - s12 * s12;
        float inv = 1.0f / det;
        float c0 =  s22 * inv;
        float c1 = -s12 * inv;
        float c2 =  s11 * inv;

        float cx = 0.5f * (mx + 1.0f) * (float)IMG_W;
        float cy = 0.5f * (my + 1.0f) * (float)IMG_H;

        float op = 1.0f / (1.0f + expf(-opacity[g]));
        // alpha = op*exp(-sigma) >= 1/255  =>  sigma <= log(255*op)
        float s_max = logf(255.0f * op);

        bool take = (s_max >= 0.0f);
        if (take) {
            // conservative bbox from covariance diagonal (+1 px safety);
            // over-coverage rejected by the exact per-pixel threshold below
            float rx = sqrtf(2.0f * s_max * s11) + 1.0f;
            float ry = sqrtf(2.0f * s_max * s22) + 1.0f;
            int w0 = (int)floorf(cx - rx - 0.5f);
            int w1 = (int)ceilf (cx + rx - 0.5f);
            int h0 = (int)floorf(cy - ry - 0.5f);
            int h1 = (int)ceilf (cy + ry - 0.5f);
            take = (w1 >= tx0) && (w0 <= tx1) && (h1 >= ty0) && (h0 <= ty1);
        }
        if (take) {
            int k = atomicAdd(&s_cnt, 1);
            s_cx[k] = cx;
            s_cy[k] = cy;
            s_h0[k] = 0.5f * c0;     // ((0.5*c0)*dx)*dx == (0.5*c0*dx)*dx, same assoc
            s_c1[k] = c1;
            s_h2[k] = 0.5f * c2;
            s_op[k] = op;
            s_cr[k] = 1.0f / (1.0f + expf(-fdc[3 * g]));
            s_cg[k] = 1.0f / (1.0f + expf(-fdc[3 * g + 1]));
            s_cb[k] = 1.0f / (1.0f + expf(-fdc[3 * g + 2]));
        }
        __syncthreads();

        // ---- eval phase: every pixel vs each survivor ----
        const int n = s_cnt;
        for (int j = 0; j < n; ++j) {
            float dx = s_cx[j] - wf;
            float dy = s_cy[j] - hf;
            // same association order as reference: (0.5c0dx^2 + 0.5c2dy^2) + c1*dy*dx
            float sigma = s_h0[j] * dx * dx + s_h2[j] * dy * dy + s_c1[j] * dy * dx;
            if (sigma < 0.0f) continue;
            float alpha = fminf(s_op[j] * expf(-sigma), 0.999f);
            if (alpha < (1.0f / 255.0f)) continue;
            accr += alpha * s_cr[j];
            accg += alpha * s_cg[j];
            accb += alpha * s_cb[j];
        }
    }

    // ---- epilogue: clip + write (folds zero_kernel and clip_kernel) ----
    const int p = y * IMG_W + x;
    out[0 * IMG_H * IMG_W + p] = fminf(fmaxf(accr, 0.0f), 1.0f);
    out[1 * IMG_H * IMG_W + p] = fminf(fmaxf(accg, 0.0f), 1.0f);
    out[2 * IMG_H * IMG_W + p] = fminf(fmaxf(accb, 0.0f), 1.0f);
}

extern "C" void kernel_launch(void* const* d_in, const int* in_sizes, int n_in,
                              void* d_out, int out_size, void* d_ws, size_t ws_size,
                              hipStream_t stream) {
    const float* xyz     = (const float*)d_in[0];  // (1, N, 2)
    const float* chol    = (const float*)d_in[1];  // (1, N, 3)
    const float* opacity = (const float*)d_in[2];  // (N, 1)
    const float* fdc     = (const float*)d_in[3];  // (N, 3)
    // d_in[4] = frame_index, always 0 (T == 1)

    float* out = (float*)d_out;                    // (1, 3, H, W)

    dim3 grid(IMG_W / TILE_W, IMG_H / TILE_H);     // (8, 64) = 512 blocks
    fused_splat_kernel<<<grid, NTHREADS, 0, stream>>>(xyz, chol, opacity, fdc, out);
}